// Round 4
// baseline (439.340 us; speedup 1.0000x reference)
//
#include <hip/hip_runtime.h>

// PixelWiseRNN: h_t = tanh(w_ih*x_t + (b_ih+b_hh) + w_hh*h_{t-1}), h_0 = 0
// x, out: (B=4, T=256, Z=16, H=64, W=64) fp32. Params: (Z,H,W) fp32.
//
// Roofline: 256 MiB read + 256 MiB write + 1 MiB params ~= 537 MB
//   -> ~82-95 us floor (harness fill kernels measure 6.53 TB/s on this chip).
// Headline dur_us anatomy (R4/R5 evidence): kernel absent from rocprof top-5
//   (all rows 1-GiB fills at ~164 us) => kernel < 164 us. 427-434 headline
//   ~= 2 fills + ~100-107 us kernel (~5.0-5.4 TB/s). Harness fills dominate.
// R2: float2 + PF8 nt load/store -> 427.2 (live). R3 PF16 -> 427.224646
//   bit-identical = STALE CACHE, never timed. R5: float4/dwordx4 -> 434.3
//   (neutral): granularity theory rejected (512B and 1KB wave-requests both
//   split into the same 128B L2 transactions).
// R6 (this round): store-ack theory. vmcnt is one in-order counter shared by
//   loads AND stores; waiting for buf[j]'s load forces completion of all older
//   interleaved nt-stores, whose ack is HBM-side. Normal (cached) stores ack
//   at L2 and write back lazily; loads stay nt so L2 is otherwise idle.
//   Also peel the last PF_D block (drop ~8 MB of clamped redundant tail loads).
// Prediction: if store-ack was throttling, headline 400-420; if null 427+-8
//   -> kernel is at effective roofline, declare.

#define RNN_B   4
#define RNN_T   256
#define RNN_ZHW 65536                 // 16*64*64
#define RNN_PG2 (RNN_ZHW / 2)         // float2 groups per image: 32768
#define PF_D    8                     // prefetch depth (T % PF_D == 0)

typedef float f32x2 __attribute__((ext_vector_type(2)));

__device__ __forceinline__ float fast_tanh(float x) {
    // tanh(x) = 1 - 2/(exp(2x)+1), exp(2x) = 2^(2*log2(e)*x)
    // Saturation: x->+inf: exp->inf, rcp->0, result 1. x->-inf: exp->0, result -1.
    float e = __builtin_amdgcn_exp2f(x * 2.885390081777927f);
    float r = __builtin_amdgcn_rcpf(e + 1.0f);
    return fmaf(-2.0f, r, 1.0f);
}

__global__ __launch_bounds__(256) void pixel_rnn_kernel(
    const float* __restrict__ x,
    const float* __restrict__ w_ih,
    const float* __restrict__ w_hh,
    const float* __restrict__ b_ih,
    const float* __restrict__ b_hh,
    float* __restrict__ out)
{
    const int g  = blockIdx.x * 256 + threadIdx.x;   // [0, B*PG2) = [0, 131072)
    const int b  = g >> 15;                          // g / RNN_PG2
    const int pg = g & (RNN_PG2 - 1);                // float2-group within image
    const int p  = pg << 1;                          // first float index

    // Per-pixel parameters (1 MB total, L2/LLC-resident; normal cached loads).
    const f32x2 wi = *(const f32x2*)(w_ih + p);
    const f32x2 wh = *(const f32x2*)(w_hh + p);
    const f32x2 bi = *(const f32x2*)(b_ih + p);
    const f32x2 bh = *(const f32x2*)(b_hh + p);
    const float bias_x = bi.x + bh.x;
    const float bias_y = bi.y + bh.y;

    // Lanes are consecutive pg -> 512 B contiguous per wave load. Blocks never
    // straddle b (32768 % 256 == 0).
    const f32x2* __restrict__ xp = (const f32x2*)x + (size_t)b * (RNN_T * RNN_PG2) + pg;
    f32x2* __restrict__ op       = (f32x2*)out     + (size_t)b * (RNN_T * RNN_PG2) + pg;

    float hx = 0.f, hy = 0.f;

    // 8-deep rotating prefetch: buf[j] holds x_{t+j}; each unrolled step
    // consumes buf[j] and issues the load for t+j+PF_D. Loads are nt (stream,
    // no L2 retention); stores are NORMAL (ack at L2, lazy write-back) so the
    // in-order vmcnt wait for buf[j] doesn't serialize on HBM-side store acks.
    f32x2 buf[PF_D];
#pragma unroll
    for (int j = 0; j < PF_D; ++j)
        buf[j] = __builtin_nontemporal_load(xp + (size_t)j * RNN_PG2);

    for (int t = 0; t < RNN_T - PF_D; t += PF_D) {
#pragma unroll
        for (int j = 0; j < PF_D; ++j) {
            const f32x2 xc = buf[j];
            buf[j] = __builtin_nontemporal_load(xp + (size_t)(t + j + PF_D) * RNN_PG2);

            hx = fast_tanh(fmaf(wi.x, xc.x, fmaf(wh.x, hx, bias_x)));
            hy = fast_tanh(fmaf(wi.y, xc.y, fmaf(wh.y, hy, bias_y)));

            f32x2 h2; h2.x = hx; h2.y = hy;
            op[(size_t)(t + j) * RNN_PG2] = h2;
        }
    }

    // Epilogue: consume the last PF_D buffered planes, no prefetch (removes
    // the clamped redundant tail loads ~8 MB).
#pragma unroll
    for (int j = 0; j < PF_D; ++j) {
        const f32x2 xc = buf[j];

        hx = fast_tanh(fmaf(wi.x, xc.x, fmaf(wh.x, hx, bias_x)));
        hy = fast_tanh(fmaf(wi.y, xc.y, fmaf(wh.y, hy, bias_y)));

        f32x2 h2; h2.x = hx; h2.y = hy;
        op[(size_t)(RNN_T - PF_D + j) * RNN_PG2] = h2;
    }
}

extern "C" void kernel_launch(void* const* d_in, const int* in_sizes, int n_in,
                              void* d_out, int out_size, void* d_ws, size_t ws_size,
                              hipStream_t stream) {
    const float* x    = (const float*)d_in[0];
    const float* w_ih = (const float*)d_in[1];
    const float* w_hh = (const float*)d_in[2];
    const float* b_ih = (const float*)d_in[3];
    const float* b_hh = (const float*)d_in[4];
    float* out        = (float*)d_out;

    // B*PG2 = 131072 threads -> 512 blocks x 256 (2 blocks/CU, 8 waves/CU).
    pixel_rnn_kernel<<<dim3(RNN_B * RNN_PG2 / 256), dim3(256), 0, stream>>>(
        x, w_ih, w_hh, b_ih, b_hh, out);
}

// Round 5
// 426.942 us; speedup vs baseline: 1.0290x; 1.0290x over previous
//
#include <hip/hip_runtime.h>

// PixelWiseRNN: h_t = tanh(w_ih*x_t + (b_ih+b_hh) + w_hh*h_{t-1}), h_0 = 0
// x, out: (B=4, T=256, Z=16, H=64, W=64) fp32. Params: (Z,H,W) fp32.
//
// Roofline: 256 MiB read + 256 MiB write + 1 MiB params ~= 537 MB
//   -> ~82-95 us floor (fills measure 6.53 TB/s; D2D copy ceiling 6.29 TB/s).
// Headline anatomy: kernel absent from rocprof top-5 (all 1-GiB fills ~164 us)
//   => kernel < 164 us; headline ~= ~330 us of harness fills + kernel.
// Live scoreboard:
//   float2 + nt/nt + PF8          -> 427.2  (kernel ~100 us, 5.4 TB/s) BEST
//   float4 + nt/nt + PF8          -> 434.3  (granularity theory rejected)
//   float2 + nt/normal-store, PF8 -> 439.3  (store-ack theory REJECTED,
//     inverted: write-allocate L2 churn makes normal stores worse; nt stores
//     bypass to the write stream. Revert to nt.)
// R7 (this round): TLP experiment at fixed in-flight bytes. float1/thread:
//   262144 threads = 1024 blocks x 256 = 16 waves/CU (4/SIMD), PF8, nt/nt.
//   32 KB/CU outstanding (same as float2 config) but 2x the independent
//   request streams -- the axis that explains float4(4w) < float2(8w).
//   Loads stay coalesced: 64 lanes x 4 B = 256 B/wave-request.
// Prediction: 415-425 if wave-count limited mixed-stream efficiency;
//   >=427 neutral -> structure space exhausted, declare roofline next round.

#define RNN_B   4
#define RNN_T   256
#define RNN_ZHW 65536                 // 16*64*64
#define PF_D    8                     // prefetch depth (T % PF_D == 0)

__device__ __forceinline__ float fast_tanh(float x) {
    // tanh(x) = 1 - 2/(exp(2x)+1), exp(2x) = 2^(2*log2(e)*x)
    // Saturation: x->+inf: exp->inf, rcp->0, result 1. x->-inf: exp->0, result -1.
    float e = __builtin_amdgcn_exp2f(x * 2.885390081777927f);
    float r = __builtin_amdgcn_rcpf(e + 1.0f);
    return fmaf(-2.0f, r, 1.0f);
}

__global__ __launch_bounds__(256) void pixel_rnn_kernel(
    const float* __restrict__ x,
    const float* __restrict__ w_ih,
    const float* __restrict__ w_hh,
    const float* __restrict__ b_ih,
    const float* __restrict__ b_hh,
    float* __restrict__ out)
{
    const int g = blockIdx.x * 256 + threadIdx.x;    // [0, B*ZHW) = [0, 262144)
    const int b = g >> 16;                           // g / RNN_ZHW
    const int p = g & (RNN_ZHW - 1);                 // pixel within image

    // Per-pixel parameters (1 MB total, L2/LLC-resident; normal cached loads).
    const float wi   = w_ih[p];
    const float wh   = w_hh[p];
    const float bias = b_ih[p] + b_hh[p];

    // Lanes are consecutive p -> 256 B contiguous per wave load. Blocks never
    // straddle b (65536 % 256 == 0).
    const float* __restrict__ xp = x   + (size_t)b * (RNN_T * RNN_ZHW) + p;
    float* __restrict__ op       = out + (size_t)b * (RNN_T * RNN_ZHW) + p;

    float h = 0.f;

    // 8-deep rotating prefetch: buf[j] holds x_{t+j}; each unrolled step
    // consumes buf[j] and issues the load for t+j+PF_D. nt on both streams
    // (no reuse; bypass L2). Fully unrolled -> all buf indices static.
    float buf[PF_D];
#pragma unroll
    for (int j = 0; j < PF_D; ++j)
        buf[j] = __builtin_nontemporal_load(xp + (size_t)j * RNN_ZHW);

    for (int t = 0; t < RNN_T - PF_D; t += PF_D) {
#pragma unroll
        for (int j = 0; j < PF_D; ++j) {
            const float xc = buf[j];
            buf[j] = __builtin_nontemporal_load(xp + (size_t)(t + j + PF_D) * RNN_ZHW);

            h = fast_tanh(fmaf(wi, xc, fmaf(wh, h, bias)));
            __builtin_nontemporal_store(h, op + (size_t)(t + j) * RNN_ZHW);
        }
    }

    // Epilogue: consume the last PF_D buffered planes, no prefetch.
#pragma unroll
    for (int j = 0; j < PF_D; ++j) {
        h = fast_tanh(fmaf(wi, buf[j], fmaf(wh, h, bias)));
        __builtin_nontemporal_store(h, op + (size_t)(RNN_T - PF_D + j) * RNN_ZHW);
    }
}

extern "C" void kernel_launch(void* const* d_in, const int* in_sizes, int n_in,
                              void* d_out, int out_size, void* d_ws, size_t ws_size,
                              hipStream_t stream) {
    const float* x    = (const float*)d_in[0];
    const float* w_ih = (const float*)d_in[1];
    const float* w_hh = (const float*)d_in[2];
    const float* b_ih = (const float*)d_in[3];
    const float* b_hh = (const float*)d_in[4];
    float* out        = (float*)d_out;

    // B*ZHW = 262144 threads -> 1024 blocks x 256 (4 blocks/CU, 16 waves/CU).
    pixel_rnn_kernel<<<dim3(RNN_B * RNN_ZHW / 256), dim3(256), 0, stream>>>(
        x, w_ih, w_hh, b_ih, b_hh, out);
}